// Round 16
// baseline (158.382 us; speedup 1.0000x reference)
//
#include <hip/hip_runtime.h>
#include <math.h>

#define D   128
#define LQ  256
#define KCQ 9
#define BQ  8
#define TQ  4096
#define RISK_DELTA 2e-5f
#define WCAP 16384
#define QPB 4   // row-quads per lag_main block: grid 2048 = 8 blocks/CU (full occ) + 4x preamble amortization

// ---------------- pk12: fused pk1+pk2 — T2 row stays in LDS, no global T2 ----------
__global__ void pk12(const float* __restrict__ wk, const float* __restrict__ wq,
                     const float* __restrict__ ctx_w, const float* __restrict__ bias_w,
                     const float* __restrict__ conv_w, const float* __restrict__ conv_b,
                     const float* __restrict__ ctx_b, const float* __restrict__ val_b,
                     const float* __restrict__ lag_embed,
                     double* __restrict__ u, int* __restrict__ wcnt,
                     double* __restrict__ g, double* __restrict__ c1,
                     float* __restrict__ ctx_wT, float* __restrict__ wqT,
                     float* __restrict__ conv_wT, float* __restrict__ baseT) {
    __shared__ double dT2[D];
    __shared__ double rowM[D];
    int tid = threadIdx.x;
    int bid = blockIdx.x;
    if (bid < D) {
        int d = bid;
        if (tid < D) {
            // T2[d][e] = sum_j wk[j][d] * wq[j][e]   (f64, same order as pk1)
            double acc = 0.0;
            for (int j = 0; j < D; ++j)
                acc += (double)wk[j * D + d] * (double)wq[j * D + tid];
            dT2[tid] = acc;
            ctx_wT[d * D + tid] = ctx_w[tid * D + d];
            wqT[d * D + tid]    = wq[tid * D + d];
            if (d < KCQ) conv_wT[d * D + tid] = conv_w[tid * KCQ + d];
        }
        baseT[d * LQ + tid] = __fadd_rn(val_b[d], lag_embed[(size_t)(tid + 1) * D + d]);
        __syncthreads();
        if (tid < D) {
            // M[d][e] = sum_j T2[d][j] * ctx_w[j][e]   (f64, same order as pk2)
            double acc = 0.0;
            for (int j = 0; j < D; ++j)
                acc += dT2[j] * (double)ctx_w[j * D + tid];
            rowM[tid] = acc;
        }
        __syncthreads();
        if (tid < KCQ) {
            double a = 0.0;
            for (int q = 0; q < D; ++q) a += rowM[q] * (double)conv_w[q * KCQ + tid];
            g[tid * D + d] = a;           // tap-major: g[k][d]
        } else if (tid == KCQ) {
            double a = 0.0;
            for (int q = 0; q < D; ++q) a += rowM[q] * (double)conv_b[q];
            for (int q = 0; q < D; ++q) a += dT2[q] * (double)ctx_b[q];
            c1[d] = a;
        }
    } else if (bid == D) {
        if (tid < D) {
            double acc = 0.0;
            for (int dd = 0; dd < D; ++dd)
                acc += (double)bias_w[dd] * (double)ctx_w[dd * D + tid];
            u[tid] = acc;
        }
    } else {
        if (tid == 0) *wcnt = 0;
    }
}

// pk3: all-f64 accumulation, emits lag_main tables in f32 (unchanged)
__global__ void pk3(const float* __restrict__ lag_embed, const float* __restrict__ val_b,
                    const float* __restrict__ val_w, const float* __restrict__ conv_w,
                    const float* __restrict__ conv_b, const float* __restrict__ ctx_b,
                    const float* __restrict__ bias_w, const float* __restrict__ bias_b,
                    const double* __restrict__ g, const double* __restrict__ c1,
                    const double* __restrict__ u,
                    float* __restrict__ gbTf, float* __restrict__ cbvf, float* __restrict__ cstf) {
    int tid = threadIdx.x;
    if (blockIdx.x < LQ) {
        __shared__ double bl[D];
        int l = blockIdx.x;
        bl[tid] = (double)val_b[tid] + (double)lag_embed[(l + 1) * D + tid];
        __syncthreads();
        if (tid < KCQ) {
            double a = 0.0;
            for (int q = 0; q < D; ++q) a += bl[q] * g[tid * D + q];
            gbTf[tid * LQ + l] = (float)a;
        } else if (tid == KCQ) {
            double a = 0.0;
            for (int q = 0; q < D; ++q) a += bl[q] * c1[q];
            cbvf[l] = (float)a;
        }
    } else {
        if (tid < KCQ) {
            double a = 0.0, a2 = 0.0;
            for (int q = 0; q < D; ++q) a  += g[tid * D + q] * (double)val_w[q];
            for (int q = 0; q < D; ++q) a2 += u[q] * (double)conv_w[q * KCQ + tid];
            cstf[tid]      = (float)a;    // sk[k]
            cstf[10 + tid] = (float)a2;   // hk[k]
        } else if (tid == KCQ) {
            double a = 0.0, a2 = 0.0;
            for (int q = 0; q < D; ++q) a  += c1[q] * (double)val_w[q];
            for (int q = 0; q < D; ++q) a2 += u[q] * (double)conv_b[q];
            for (int q = 0; q < D; ++q) a2 += (double)bias_w[q] * (double)ctx_b[q];
            cstf[9]  = (float)a;                          // ssc
            cstf[19] = (float)(a2 + (double)bias_b[0]);   // hc (incl. bias_b)
        }
    }
}

// ---------------- main kernel: r13 body + QPB=4 (full occupancy + amortized tables) -
__global__ __launch_bounds__(256, 8) void lag_main(
    const float* __restrict__ x, const float* __restrict__ gbTf,
    const float* __restrict__ cbvf, const float* __restrict__ cstf,
    float* __restrict__ muOut, float* __restrict__ wOut,
    int* __restrict__ wcnt, int* __restrict__ wlist) {
    __shared__ float sgb[KCQ * LQ];
    __shared__ float scb[LQ];
    __shared__ float sc[20];
    int tid = threadIdx.x;
    #pragma unroll
    for (int i = 0; i < KCQ; ++i) sgb[i * LQ + tid] = gbTf[i * LQ + tid];
    scb[tid] = cbvf[tid];
    if (tid < 20) sc[tid] = cstf[tid];
    __syncthreads();

    int wave = tid >> 6, lane = tid & 63;
    int l0 = lane * 4;
    const float4 cb4 = *reinterpret_cast<const float4*>(&scb[l0]);  // row-independent
    const float NEG_INF = -__builtin_inff();

    #pragma unroll 1
    for (int it0 = 0; it0 < QPB; ++it0) {
        int row = (blockIdx.x * QPB + it0) * 4 + wave;
        int b = row >> 12;
        int t = row & (TQ - 1);
        const float* xb = x + b * TQ;

        float xw[KCQ];
        #pragma unroll
        for (int k = 0; k < KCQ; ++k) {
            int idx = t - 8 + k;
            xw[k] = (idx >= 0) ? xb[idx] : 0.f;
        }
        float s = sc[9], bias = sc[19];
        #pragma unroll
        for (int k = 0; k < KCQ; ++k) {
            s    = fmaf(sc[k],      xw[k], s);
            bias = fmaf(sc[10 + k], xw[k], bias);
        }

        float xlag[4];
        #pragma unroll
        for (int i = 0; i < 4; ++i) {
            int idx = t - 1 - (l0 + i);
            xlag[i] = (idx >= 0) ? xb[idx] : 0.f;
        }

        float lg[4] = {cb4.x, cb4.y, cb4.z, cb4.w};
        #pragma unroll
        for (int k = 0; k < KCQ; ++k) {
            float4 g4 = *reinterpret_cast<const float4*>(&sgb[k * LQ + l0]);
            lg[0] = fmaf(g4.x, xw[k], lg[0]);
            lg[1] = fmaf(g4.y, xw[k], lg[1]);
            lg[2] = fmaf(g4.z, xw[k], lg[2]);
            lg[3] = fmaf(g4.w, xw[k], lg[3]);
        }
        #pragma unroll
        for (int i = 0; i < 4; ++i) lg[i] = fmaf(xlag[i], s, lg[i]);

        // top-9: mx (1st), thr (8th), v9 (9th); ballot-free removal (ties measure-zero)
        float wl0 = lg[0], wl1 = lg[1], wl2 = lg[2], wl3 = lg[3];
        float mx = 0.f, thr = 0.f, v9 = 0.f;
        #pragma unroll
        for (int it = 0; it < 9; ++it) {
            float lm = fmaxf(fmaxf(wl0, wl1), fmaxf(wl2, wl3));
            float m = lm;
            #pragma unroll
            for (int off = 32; off >= 1; off >>= 1)
                m = fmaxf(m, __shfl_xor(m, off, 64));
            if (it == 0) mx = m;
            if (it == 7) thr = m;
            if (it == 8) v9 = m;
            if (it < 8) {
                wl0 = (wl0 == m) ? NEG_INF : wl0;
                wl1 = (wl1 == m) ? NEG_INF : wl1;
                wl2 = (wl2 == m) ? NEG_INF : wl2;
                wl3 = (wl3 == m) ? NEG_INF : wl3;
            }
        }

        bool defer = false;
        if ((thr - v9) < RISK_DELTA) {
            int pos = 0;
            if (lane == 0) pos = atomicAdd(wcnt, 1);
            pos = __shfl(pos, 0, 64);
            if (pos < WCAP) {
                if (lane == 0) wlist[pos] = row;
                defer = true;
            }
        }
        if (!defer) {
            float p[4], psum = 0.f, pmu = 0.f;
            #pragma unroll
            for (int j = 0; j < 4; ++j) {
                p[j] = (lg[j] >= thr) ? __expf(lg[j] - mx) : 0.f;
                psum += p[j];
                pmu = fmaf(p[j], xlag[j], pmu);
            }
            #pragma unroll
            for (int off = 32; off >= 1; off >>= 1) {
                psum += __shfl_xor(psum, off, 64);
                pmu  += __shfl_xor(pmu,  off, 64);
            }
            float inv = 1.f / psum;
            float4 wo = make_float4(p[0] * inv, p[1] * inv, p[2] * inv, p[3] * inv);
            *reinterpret_cast<float4*>(&wOut[(size_t)row * LQ + l0]) = wo;
            if (lane == 0) muOut[row] = fmaf(pmu, inv, bias);
        }
    }
}

// ---------------- fixer: r15 verbatim (512 threads, 2-row chains, no spill) --------
__global__ __launch_bounds__(512) void fixer(
    const float* __restrict__ x, const float* __restrict__ wk,
    const float* __restrict__ val_w, const float* __restrict__ conv_b,
    const float* __restrict__ ctx_b, const float* __restrict__ bias_w,
    const float* __restrict__ bias_b,
    const float* __restrict__ ctx_wT, const float* __restrict__ wqT,
    const float* __restrict__ conv_wT, const float* __restrict__ baseT,
    const int* __restrict__ wcnt, const int* __restrict__ wlist,
    float* __restrict__ muOut, float* __restrict__ wOut) {
    __shared__ float sxw[8][KCQ];
    __shared__ float sctxc[8][D];
    __shared__ float sctxp[8][D];
    __shared__ float sq[8][D];
    __shared__ float sqk[8][D];
    __shared__ float ssv[8];
    __shared__ float sbd[8];
    __shared__ float slog[8][LQ];
    __shared__ int   srow[8];

    int cnt = *wcnt;
    if (cnt > WCAP) cnt = WCAP;
    int ngroups = (cnt + 7) >> 3;
    int tid = threadIdx.x;

    for (int gi = blockIdx.x; gi < ngroups; gi += gridDim.x) {
        if (tid < 8) {
            int idx = gi * 8 + tid;
            if (idx >= cnt) idx = cnt - 1;   // pad with last row (duplicate write benign)
            srow[tid] = wlist[idx];
        }
        __syncthreads();
        if (tid < 8 * KCQ) {
            int g = tid / KCQ, k = tid % KCQ;
            int row = srow[g]; int b = row >> 12, t = row & (TQ - 1);
            int ii = t - 8 + k;
            sxw[g][k] = (ii >= 0) ? x[b * TQ + ii] : 0.f;
        }
        __syncthreads();

        // stage 1: conv — thread handles rows r and r+4 at element d
        {
            int d = tid & (D - 1), r = (tid >> 7) & 3;
            float cw[KCQ];
            #pragma unroll
            for (int k = 0; k < KCQ; ++k) cw[k] = conv_wT[k * D + d];
            float a0 = 0.f, a1 = 0.f;
            #pragma unroll
            for (int k = 0; k < KCQ; ++k) {
                a0 = fmaf(cw[k], sxw[r][k], a0);
                a1 = fmaf(cw[k], sxw[r + 4][k], a1);
            }
            float cb = conv_b[d];
            sctxc[r][d]     = __fadd_rn(a0, cb);
            sctxc[r + 4][d] = __fadd_rn(a1, cb);
        }
        __syncthreads();

        // stage 2: ctx_proj — 2 chains/thread, dbuf 16-batches
        {
            int e = tid & (D - 1), r = (tid >> 7) & 3;
            float a0 = 0.f, a1 = 0.f;
            float wv0[16], wv1[16];
            #pragma unroll
            for (int u = 0; u < 16; ++u) wv0[u] = ctx_wT[u * D + e];
            #pragma unroll 1
            for (int d2 = 0; d2 < D; d2 += 32) {
                #pragma unroll
                for (int u = 0; u < 16; ++u) wv1[u] = ctx_wT[(d2 + 16 + u) * D + e];
                #pragma unroll
                for (int u = 0; u < 16; ++u) {
                    a0 = fmaf(wv0[u], sctxc[r][d2 + u], a0);
                    a1 = fmaf(wv0[u], sctxc[r + 4][d2 + u], a1);
                }
                if (d2 + 32 < D) {
                    #pragma unroll
                    for (int u = 0; u < 16; ++u) wv0[u] = ctx_wT[(d2 + 32 + u) * D + e];
                }
                #pragma unroll
                for (int u = 0; u < 16; ++u) {
                    a0 = fmaf(wv1[u], sctxc[r][d2 + 16 + u], a0);
                    a1 = fmaf(wv1[u], sctxc[r + 4][d2 + 16 + u], a1);
                }
            }
            float cb = ctx_b[e];
            sctxp[r][e]     = __fadd_rn(a0, cb);
            sctxp[r + 4][e] = __fadd_rn(a1, cb);
        }
        __syncthreads();

        // stage 3: q = ctx @ wq.T — 2 chains/thread
        {
            int e = tid & (D - 1), r = (tid >> 7) & 3;
            float a0 = 0.f, a1 = 0.f;
            float wv0[16], wv1[16];
            #pragma unroll
            for (int u = 0; u < 16; ++u) wv0[u] = wqT[u * D + e];
            #pragma unroll 1
            for (int e2 = 0; e2 < D; e2 += 32) {
                #pragma unroll
                for (int u = 0; u < 16; ++u) wv1[u] = wqT[(e2 + 16 + u) * D + e];
                #pragma unroll
                for (int u = 0; u < 16; ++u) {
                    a0 = fmaf(wv0[u], sctxp[r][e2 + u], a0);
                    a1 = fmaf(wv0[u], sctxp[r + 4][e2 + u], a1);
                }
                if (e2 + 32 < D) {
                    #pragma unroll
                    for (int u = 0; u < 16; ++u) wv0[u] = wqT[(e2 + 32 + u) * D + e];
                }
                #pragma unroll
                for (int u = 0; u < 16; ++u) {
                    a0 = fmaf(wv1[u], sctxp[r][e2 + 16 + u], a0);
                    a1 = fmaf(wv1[u], sctxp[r + 4][e2 + 16 + u], a1);
                }
            }
            sq[r][e]     = a0;
            sq[r + 4][e] = a1;
        }
        __syncthreads();

        // stage 4: qk = q @ wk — 2 chains/thread
        {
            int e = tid & (D - 1), r = (tid >> 7) & 3;
            float a0 = 0.f, a1 = 0.f;
            float wv0[16], wv1[16];
            #pragma unroll
            for (int u = 0; u < 16; ++u) wv0[u] = wk[u * D + e];
            #pragma unroll 1
            for (int a2i = 0; a2i < D; a2i += 32) {
                #pragma unroll
                for (int u = 0; u < 16; ++u) wv1[u] = wk[(a2i + 16 + u) * D + e];
                #pragma unroll
                for (int u = 0; u < 16; ++u) {
                    a0 = fmaf(wv0[u], sq[r][a2i + u], a0);
                    a1 = fmaf(wv0[u], sq[r + 4][a2i + u], a1);
                }
                if (a2i + 32 < D) {
                    #pragma unroll
                    for (int u = 0; u < 16; ++u) wv0[u] = wk[(a2i + 32 + u) * D + e];
                }
                #pragma unroll
                for (int u = 0; u < 16; ++u) {
                    a0 = fmaf(wv1[u], sq[r][a2i + 16 + u], a0);
                    a1 = fmaf(wv1[u], sq[r + 4][a2i + 16 + u], a1);
                }
            }
            sqk[r][e]     = a0;
            sqk[r + 4][e] = a1;
        }
        __syncthreads();

        // mini-stage: s = qk·val_w (tid<8) ; biasdot = ctxp·bias_w (tid 8..15) — batched
        if (tid < 8) {
            int g = tid;
            float a = 0.f;
            #pragma unroll 1
            for (int d2 = 0; d2 < D; d2 += 16) {
                float vv[16];
                #pragma unroll
                for (int u = 0; u < 16; ++u) vv[u] = val_w[d2 + u];
                #pragma unroll
                for (int u = 0; u < 16; ++u) a = fmaf(sqk[g][d2 + u], vv[u], a);
            }
            ssv[g] = a;
        } else if (tid < 16) {
            int g = tid - 8;
            float a = 0.f;
            #pragma unroll 1
            for (int e2 = 0; e2 < D; e2 += 16) {
                float vv[16];
                #pragma unroll
                for (int u = 0; u < 16; ++u) vv[u] = bias_w[e2 + u];
                #pragma unroll
                for (int u = 0; u < 16; ++u) a = fmaf(sctxp[g][e2 + u], vv[u], a);
            }
            sbd[g] = a;
        }
        __syncthreads();

        // logits: thread handles l = tid&255 for rows h*4..h*4+3 (h = tid>>8), dbuf loads
        {
            int l = tid & (LQ - 1);
            int h = tid >> 8;                 // 0..1
            int r0 = h * 4;
            float c0 = 0.f, c1v = 0.f, c2 = 0.f, c3 = 0.f;
            float bd0[16], bd1[16];
            #pragma unroll
            for (int u = 0; u < 16; ++u) bd0[u] = baseT[u * LQ + l];
            #pragma unroll 1
            for (int d2 = 0; d2 < D; d2 += 32) {
                #pragma unroll
                for (int u = 0; u < 16; ++u) bd1[u] = baseT[(d2 + 16 + u) * LQ + l];
                #pragma unroll
                for (int u = 0; u < 16; ++u) {
                    float bd = bd0[u];
                    c0  = fmaf(bd, sqk[r0 + 0][d2 + u], c0);
                    c1v = fmaf(bd, sqk[r0 + 1][d2 + u], c1v);
                    c2  = fmaf(bd, sqk[r0 + 2][d2 + u], c2);
                    c3  = fmaf(bd, sqk[r0 + 3][d2 + u], c3);
                }
                if (d2 + 32 < D) {
                    #pragma unroll
                    for (int u = 0; u < 16; ++u) bd0[u] = baseT[(d2 + 32 + u) * LQ + l];
                }
                #pragma unroll
                for (int u = 0; u < 16; ++u) {
                    float bd = bd1[u];
                    c0  = fmaf(bd, sqk[r0 + 0][d2 + 16 + u], c0);
                    c1v = fmaf(bd, sqk[r0 + 1][d2 + 16 + u], c1v);
                    c2  = fmaf(bd, sqk[r0 + 2][d2 + 16 + u], c2);
                    c3  = fmaf(bd, sqk[r0 + 3][d2 + 16 + u], c3);
                }
            }
            float accs[4] = {c0, c1v, c2, c3};
            #pragma unroll
            for (int j = 0; j < 4; ++j) {
                int g = r0 + j;
                int row = srow[g]; int b = row >> 12, t = row & (TQ - 1);
                int ii = t - 1 - l;
                float xl = (ii >= 0) ? x[b * TQ + ii] : 0.f;
                slog[g][l] = __fadd_rn(__fmul_rn(xl, ssv[g]), accs[j]);
            }
        }
        __syncthreads();

        // top-8 + softmax + writes: wave w handles row w (8 waves, all busy)
        {
            int wv = tid >> 6, lane = tid & 63;
            int gg = wv;
            float lv0 = slog[gg][lane], lv1 = slog[gg][lane + 64];
            float lv2 = slog[gg][lane + 128], lv3 = slog[gg][lane + 192];
            const float NEG_INF = -__builtin_inff();
            float w0 = lv0, w1 = lv1, w2 = lv2, w3 = lv3;
            float mx = 0.f, thr = 0.f;
            #pragma unroll
            for (int it = 0; it < 8; ++it) {
                float lm = fmaxf(fmaxf(w0, w1), fmaxf(w2, w3));
                float m = lm;
                #pragma unroll
                for (int off = 32; off >= 1; off >>= 1)
                    m = fmaxf(m, __shfl_xor(m, off, 64));
                if (it == 0) mx = m;
                thr = m;
                if (it < 7) {
                    unsigned long long ball = __ballot(lm == m);
                    int leader = __ffsll(ball) - 1;
                    if (lane == leader) {
                        if (w0 == m)      w0 = NEG_INF;
                        else if (w1 == m) w1 = NEG_INF;
                        else if (w2 == m) w2 = NEG_INF;
                        else              w3 = NEG_INF;
                    }
                }
            }
            int row = srow[gg]; int b = row >> 12, t = row & (TQ - 1);
            float p[4], xlg[4];
            double ps = 0.0;
            float lvs[4] = {lv0, lv1, lv2, lv3};
            #pragma unroll
            for (int j = 0; j < 4; ++j) {
                int l = lane + 64 * j;
                int ii = t - 1 - l;
                xlg[j] = (ii >= 0) ? x[b * TQ + ii] : 0.f;
                p[j] = (lvs[j] >= thr) ? (float)exp((double)__fsub_rn(lvs[j], mx)) : 0.f;
                ps += (double)p[j];
            }
            #pragma unroll
            for (int off = 32; off >= 1; off >>= 1)
                ps += __shfl_xor(ps, off, 64);
            float psf = (float)ps;
            double mud = 0.0;
            #pragma unroll
            for (int j = 0; j < 4; ++j) {
                float wvv = __fdiv_rn(p[j], psf);
                wOut[(size_t)row * LQ + lane + 64 * j] = wvv;
                mud += (double)__fmul_rn(wvv, xlg[j]);
            }
            #pragma unroll
            for (int off = 32; off >= 1; off >>= 1)
                mud += __shfl_xor(mud, off, 64);
            if (lane == 0) {
                float m1 = (float)mud;
                m1 = __fadd_rn(m1, sbd[gg]);
                m1 = __fadd_rn(m1, bias_b[0]);
                muOut[row] = m1;
            }
        }
        __syncthreads();
    }
}

extern "C" void kernel_launch(void* const* d_in, const int* in_sizes, int n_in,
                              void* d_out, int out_size, void* d_ws, size_t ws_size,
                              hipStream_t stream) {
    const float* x         = (const float*)d_in[0];
    const float* lag_embed = (const float*)d_in[1];
    const float* val_w     = (const float*)d_in[2];
    const float* val_b     = (const float*)d_in[3];
    const float* conv_w    = (const float*)d_in[4];
    const float* conv_b    = (const float*)d_in[5];
    const float* ctx_w     = (const float*)d_in[6];
    const float* ctx_b     = (const float*)d_in[7];
    const float* wq        = (const float*)d_in[8];
    const float* wk        = (const float*)d_in[9];
    const float* bias_w    = (const float*)d_in[10];
    const float* bias_b    = (const float*)d_in[11];

    char* wsb = (char*)d_ws;
    double* T2  = (double*)wsb;     // (unused slot kept for layout stability)
    double* g   = T2 + 16384;       // 1152 d
    double* u   = g + 1152;         // 128 d
    double* c1  = u + 128;          // 128 d
    float* gbTf = (float*)(c1 + 128);  // 2304 f
    float* cbvf = gbTf + 2304;         // 256 f
    float* cstf = cbvf + 256;          // 20 f
    int* wcnt  = (int*)(wsb + 163840);
    int* wlist = wcnt + 1;          // WCAP=16384 ints
    float* ctx_wT  = (float*)(wsb + 229504);   // 16384 f
    float* wqT     = ctx_wT + 16384;           // 16384 f
    float* conv_wT = wqT + 16384;              // 1152 f
    float* baseT   = conv_wT + 1152;           // 32768 f

    float* muOut = (float*)d_out;
    float* wOut  = muOut + BQ * TQ;

    hipLaunchKernelGGL(pk12, dim3(D + 2), dim3(256), 0, stream,
                       wk, wq, ctx_w, bias_w, conv_w, conv_b, ctx_b, val_b, lag_embed,
                       u, wcnt, g, c1, ctx_wT, wqT, conv_wT, baseT);
    hipLaunchKernelGGL(pk3, dim3(LQ + 1), dim3(D), 0, stream,
                       lag_embed, val_b, val_w, conv_w, conv_b, ctx_b, bias_w, bias_b,
                       g, c1, u, gbTf, cbvf, cstf);
    hipLaunchKernelGGL(lag_main, dim3(BQ * TQ / (4 * QPB)), dim3(256), 0, stream,
                       x, gbTf, cbvf, cstf, muOut, wOut, wcnt, wlist);
    hipLaunchKernelGGL(fixer, dim3(256), dim3(512), 0, stream,
                       x, wk, val_w, conv_b, ctx_b, bias_w, bias_b,
                       ctx_wT, wqT, conv_wT, baseT, wcnt, wlist, muOut, wOut);
}

// Round 17
// 89.899 us; speedup vs baseline: 1.7618x; 1.7618x over previous
//
#include <hip/hip_runtime.h>
#include <math.h>

#define D   128
#define LQ  256
#define KCQ 9
#define BQ  8
#define TQ  4096
#define RISK_DELTA 2e-5f
#define WCAP 16384

// ---------------- pk12: fused pk1+pk2 — T2 row stays in LDS, no global T2 ----------
__global__ void pk12(const float* __restrict__ wk, const float* __restrict__ wq,
                     const float* __restrict__ ctx_w, const float* __restrict__ bias_w,
                     const float* __restrict__ conv_w, const float* __restrict__ conv_b,
                     const float* __restrict__ ctx_b, const float* __restrict__ val_b,
                     const float* __restrict__ lag_embed,
                     double* __restrict__ u, int* __restrict__ wcnt,
                     double* __restrict__ g, double* __restrict__ c1,
                     float* __restrict__ ctx_wT, float* __restrict__ wqT,
                     float* __restrict__ conv_wT, float* __restrict__ baseT) {
    __shared__ double dT2[D];
    __shared__ double rowM[D];
    int tid = threadIdx.x;
    int bid = blockIdx.x;
    if (bid < D) {
        int d = bid;
        if (tid < D) {
            // T2[d][e] = sum_j wk[j][d] * wq[j][e]   (f64, same order as pk1)
            double acc = 0.0;
            for (int j = 0; j < D; ++j)
                acc += (double)wk[j * D + d] * (double)wq[j * D + tid];
            dT2[tid] = acc;
            ctx_wT[d * D + tid] = ctx_w[tid * D + d];
            wqT[d * D + tid]    = wq[tid * D + d];
            if (d < KCQ) conv_wT[d * D + tid] = conv_w[tid * KCQ + d];
        }
        baseT[d * LQ + tid] = __fadd_rn(val_b[d], lag_embed[(size_t)(tid + 1) * D + d]);
        __syncthreads();
        if (tid < D) {
            // M[d][e] = sum_j T2[d][j] * ctx_w[j][e]   (f64, same order as pk2)
            double acc = 0.0;
            for (int j = 0; j < D; ++j)
                acc += dT2[j] * (double)ctx_w[j * D + tid];
            rowM[tid] = acc;
        }
        __syncthreads();
        if (tid < KCQ) {
            double a = 0.0;
            for (int q = 0; q < D; ++q) a += rowM[q] * (double)conv_w[q * KCQ + tid];
            g[tid * D + d] = a;           // tap-major: g[k][d]
        } else if (tid == KCQ) {
            double a = 0.0;
            for (int q = 0; q < D; ++q) a += rowM[q] * (double)conv_b[q];
            for (int q = 0; q < D; ++q) a += dT2[q] * (double)ctx_b[q];
            c1[d] = a;
        }
    } else if (bid == D) {
        if (tid < D) {
            double acc = 0.0;
            for (int dd = 0; dd < D; ++dd)
                acc += (double)bias_w[dd] * (double)ctx_w[dd * D + tid];
            u[tid] = acc;
        }
    } else {
        if (tid == 0) *wcnt = 0;
    }
}

// pk3: all-f64 accumulation, emits lag_main tables in f32 (unchanged)
__global__ void pk3(const float* __restrict__ lag_embed, const float* __restrict__ val_b,
                    const float* __restrict__ val_w, const float* __restrict__ conv_w,
                    const float* __restrict__ conv_b, const float* __restrict__ ctx_b,
                    const float* __restrict__ bias_w, const float* __restrict__ bias_b,
                    const double* __restrict__ g, const double* __restrict__ c1,
                    const double* __restrict__ u,
                    float* __restrict__ gbTf, float* __restrict__ cbvf, float* __restrict__ cstf) {
    int tid = threadIdx.x;
    if (blockIdx.x < LQ) {
        __shared__ double bl[D];
        int l = blockIdx.x;
        bl[tid] = (double)val_b[tid] + (double)lag_embed[(l + 1) * D + tid];
        __syncthreads();
        if (tid < KCQ) {
            double a = 0.0;
            for (int q = 0; q < D; ++q) a += bl[q] * g[tid * D + q];
            gbTf[tid * LQ + l] = (float)a;
        } else if (tid == KCQ) {
            double a = 0.0;
            for (int q = 0; q < D; ++q) a += bl[q] * c1[q];
            cbvf[l] = (float)a;
        }
    } else {
        if (tid < KCQ) {
            double a = 0.0, a2 = 0.0;
            for (int q = 0; q < D; ++q) a  += g[tid * D + q] * (double)val_w[q];
            for (int q = 0; q < D; ++q) a2 += u[q] * (double)conv_w[q * KCQ + tid];
            cstf[tid]      = (float)a;    // sk[k]
            cstf[10 + tid] = (float)a2;   // hk[k]
        } else if (tid == KCQ) {
            double a = 0.0, a2 = 0.0;
            for (int q = 0; q < D; ++q) a  += c1[q] * (double)val_w[q];
            for (int q = 0; q < D; ++q) a2 += u[q] * (double)conv_b[q];
            for (int q = 0; q < D; ++q) a2 += (double)bias_w[q] * (double)ctx_b[q];
            cstf[9]  = (float)a;                          // ssc
            cstf[19] = (float)(a2 + (double)bias_b[0]);   // hc (incl. bias_b)
        }
    }
}

// ---------------- main kernel: r13 verbatim (straight-line, grid 8192) -------------
__global__ __launch_bounds__(256, 8) void lag_main(
    const float* __restrict__ x, const float* __restrict__ gbTf,
    const float* __restrict__ cbvf, const float* __restrict__ cstf,
    float* __restrict__ muOut, float* __restrict__ wOut,
    int* __restrict__ wcnt, int* __restrict__ wlist) {
    __shared__ float sgb[KCQ * LQ];
    __shared__ float scb[LQ];
    __shared__ float sc[20];
    int tid = threadIdx.x;
    #pragma unroll
    for (int i = 0; i < KCQ; ++i) sgb[i * LQ + tid] = gbTf[i * LQ + tid];
    scb[tid] = cbvf[tid];
    if (tid < 20) sc[tid] = cstf[tid];
    __syncthreads();

    int wave = tid >> 6, lane = tid & 63;
    int row = blockIdx.x * 4 + wave;
    int b = row >> 12;
    int t = row & (TQ - 1);
    const float* xb = x + b * TQ;

    float xw[KCQ];
    #pragma unroll
    for (int k = 0; k < KCQ; ++k) {
        int idx = t - 8 + k;
        xw[k] = (idx >= 0) ? xb[idx] : 0.f;
    }
    float s = sc[9], bias = sc[19];
    #pragma unroll
    for (int k = 0; k < KCQ; ++k) {
        s    = fmaf(sc[k],      xw[k], s);
        bias = fmaf(sc[10 + k], xw[k], bias);
    }

    int l0 = lane * 4;
    float xlag[4];
    #pragma unroll
    for (int i = 0; i < 4; ++i) {
        int idx = t - 1 - (l0 + i);
        xlag[i] = (idx >= 0) ? xb[idx] : 0.f;
    }

    float4 cb4 = *reinterpret_cast<const float4*>(&scb[l0]);
    float lg[4] = {cb4.x, cb4.y, cb4.z, cb4.w};
    #pragma unroll
    for (int k = 0; k < KCQ; ++k) {
        float4 g4 = *reinterpret_cast<const float4*>(&sgb[k * LQ + l0]);
        lg[0] = fmaf(g4.x, xw[k], lg[0]);
        lg[1] = fmaf(g4.y, xw[k], lg[1]);
        lg[2] = fmaf(g4.z, xw[k], lg[2]);
        lg[3] = fmaf(g4.w, xw[k], lg[3]);
    }
    #pragma unroll
    for (int i = 0; i < 4; ++i) lg[i] = fmaf(xlag[i], s, lg[i]);

    const float NEG_INF = -__builtin_inff();
    float wl0 = lg[0], wl1 = lg[1], wl2 = lg[2], wl3 = lg[3];
    float mx = 0.f, thr = 0.f, v9 = 0.f;
    #pragma unroll
    for (int it = 0; it < 9; ++it) {
        float lm = fmaxf(fmaxf(wl0, wl1), fmaxf(wl2, wl3));
        float m = lm;
        #pragma unroll
        for (int off = 32; off >= 1; off >>= 1)
            m = fmaxf(m, __shfl_xor(m, off, 64));
        if (it == 0) mx = m;
        if (it == 7) thr = m;
        if (it == 8) v9 = m;
        if (it < 8) {
            wl0 = (wl0 == m) ? NEG_INF : wl0;
            wl1 = (wl1 == m) ? NEG_INF : wl1;
            wl2 = (wl2 == m) ? NEG_INF : wl2;
            wl3 = (wl3 == m) ? NEG_INF : wl3;
        }
    }

    if ((thr - v9) < RISK_DELTA) {
        if (lane == 0) {
            int pos = atomicAdd(wcnt, 1);
            if (pos < WCAP) wlist[pos] = row;
        }
        return;
    }

    float p[4], psum = 0.f, pmu = 0.f;
    #pragma unroll
    for (int j = 0; j < 4; ++j) {
        p[j] = (lg[j] >= thr) ? __expf(lg[j] - mx) : 0.f;
        psum += p[j];
        pmu = fmaf(p[j], xlag[j], pmu);
    }
    #pragma unroll
    for (int off = 32; off >= 1; off >>= 1) {
        psum += __shfl_xor(psum, off, 64);
        pmu  += __shfl_xor(pmu,  off, 64);
    }
    float inv = 1.f / psum;
    float4 wo = make_float4(p[0] * inv, p[1] * inv, p[2] * inv, p[3] * inv);
    *reinterpret_cast<float4*>(&wOut[(size_t)row * LQ + l0]) = wo;
    if (lane == 0) muOut[row] = fmaf(pmu, inv, bias);
}

// ---------------- fixer: r15 verbatim (512 threads, 2-row chains, no spill) --------
__global__ __launch_bounds__(512) void fixer(
    const float* __restrict__ x, const float* __restrict__ wk,
    const float* __restrict__ val_w, const float* __restrict__ conv_b,
    const float* __restrict__ ctx_b, const float* __restrict__ bias_w,
    const float* __restrict__ bias_b,
    const float* __restrict__ ctx_wT, const float* __restrict__ wqT,
    const float* __restrict__ conv_wT, const float* __restrict__ baseT,
    const int* __restrict__ wcnt, const int* __restrict__ wlist,
    float* __restrict__ muOut, float* __restrict__ wOut) {
    __shared__ float sxw[8][KCQ];
    __shared__ float sctxc[8][D];
    __shared__ float sctxp[8][D];
    __shared__ float sq[8][D];
    __shared__ float sqk[8][D];
    __shared__ float ssv[8];
    __shared__ float sbd[8];
    __shared__ float slog[8][LQ];
    __shared__ int   srow[8];

    int cnt = *wcnt;
    if (cnt > WCAP) cnt = WCAP;
    int ngroups = (cnt + 7) >> 3;
    int tid = threadIdx.x;

    for (int gi = blockIdx.x; gi < ngroups; gi += gridDim.x) {
        if (tid < 8) {
            int idx = gi * 8 + tid;
            if (idx >= cnt) idx = cnt - 1;   // pad with last row (duplicate write benign)
            srow[tid] = wlist[idx];
        }
        __syncthreads();
        if (tid < 8 * KCQ) {
            int g = tid / KCQ, k = tid % KCQ;
            int row = srow[g]; int b = row >> 12, t = row & (TQ - 1);
            int ii = t - 8 + k;
            sxw[g][k] = (ii >= 0) ? x[b * TQ + ii] : 0.f;
        }
        __syncthreads();

        // stage 1: conv — thread handles rows r and r+4 at element d
        {
            int d = tid & (D - 1), r = (tid >> 7) & 3;
            float cw[KCQ];
            #pragma unroll
            for (int k = 0; k < KCQ; ++k) cw[k] = conv_wT[k * D + d];
            float a0 = 0.f, a1 = 0.f;
            #pragma unroll
            for (int k = 0; k < KCQ; ++k) {
                a0 = fmaf(cw[k], sxw[r][k], a0);
                a1 = fmaf(cw[k], sxw[r + 4][k], a1);
            }
            float cb = conv_b[d];
            sctxc[r][d]     = __fadd_rn(a0, cb);
            sctxc[r + 4][d] = __fadd_rn(a1, cb);
        }
        __syncthreads();

        // stage 2: ctx_proj — 2 chains/thread, dbuf 16-batches
        {
            int e = tid & (D - 1), r = (tid >> 7) & 3;
            float a0 = 0.f, a1 = 0.f;
            float wv0[16], wv1[16];
            #pragma unroll
            for (int u = 0; u < 16; ++u) wv0[u] = ctx_wT[u * D + e];
            #pragma unroll 1
            for (int d2 = 0; d2 < D; d2 += 32) {
                #pragma unroll
                for (int u = 0; u < 16; ++u) wv1[u] = ctx_wT[(d2 + 16 + u) * D + e];
                #pragma unroll
                for (int u = 0; u < 16; ++u) {
                    a0 = fmaf(wv0[u], sctxc[r][d2 + u], a0);
                    a1 = fmaf(wv0[u], sctxc[r + 4][d2 + u], a1);
                }
                if (d2 + 32 < D) {
                    #pragma unroll
                    for (int u = 0; u < 16; ++u) wv0[u] = ctx_wT[(d2 + 32 + u) * D + e];
                }
                #pragma unroll
                for (int u = 0; u < 16; ++u) {
                    a0 = fmaf(wv1[u], sctxc[r][d2 + 16 + u], a0);
                    a1 = fmaf(wv1[u], sctxc[r + 4][d2 + 16 + u], a1);
                }
            }
            float cb = ctx_b[e];
            sctxp[r][e]     = __fadd_rn(a0, cb);
            sctxp[r + 4][e] = __fadd_rn(a1, cb);
        }
        __syncthreads();

        // stage 3: q = ctx @ wq.T — 2 chains/thread
        {
            int e = tid & (D - 1), r = (tid >> 7) & 3;
            float a0 = 0.f, a1 = 0.f;
            float wv0[16], wv1[16];
            #pragma unroll
            for (int u = 0; u < 16; ++u) wv0[u] = wqT[u * D + e];
            #pragma unroll 1
            for (int e2 = 0; e2 < D; e2 += 32) {
                #pragma unroll
                for (int u = 0; u < 16; ++u) wv1[u] = wqT[(e2 + 16 + u) * D + e];
                #pragma unroll
                for (int u = 0; u < 16; ++u) {
                    a0 = fmaf(wv0[u], sctxp[r][e2 + u], a0);
                    a1 = fmaf(wv0[u], sctxp[r + 4][e2 + u], a1);
                }
                if (e2 + 32 < D) {
                    #pragma unroll
                    for (int u = 0; u < 16; ++u) wv0[u] = wqT[(e2 + 32 + u) * D + e];
                }
                #pragma unroll
                for (int u = 0; u < 16; ++u) {
                    a0 = fmaf(wv1[u], sctxp[r][e2 + 16 + u], a0);
                    a1 = fmaf(wv1[u], sctxp[r + 4][e2 + 16 + u], a1);
                }
            }
            sq[r][e]     = a0;
            sq[r + 4][e] = a1;
        }
        __syncthreads();

        // stage 4: qk = q @ wk — 2 chains/thread
        {
            int e = tid & (D - 1), r = (tid >> 7) & 3;
            float a0 = 0.f, a1 = 0.f;
            float wv0[16], wv1[16];
            #pragma unroll
            for (int u = 0; u < 16; ++u) wv0[u] = wk[u * D + e];
            #pragma unroll 1
            for (int a2i = 0; a2i < D; a2i += 32) {
                #pragma unroll
                for (int u = 0; u < 16; ++u) wv1[u] = wk[(a2i + 16 + u) * D + e];
                #pragma unroll
                for (int u = 0; u < 16; ++u) {
                    a0 = fmaf(wv0[u], sq[r][a2i + u], a0);
                    a1 = fmaf(wv0[u], sq[r + 4][a2i + u], a1);
                }
                if (a2i + 32 < D) {
                    #pragma unroll
                    for (int u = 0; u < 16; ++u) wv0[u] = wk[(a2i + 32 + u) * D + e];
                }
                #pragma unroll
                for (int u = 0; u < 16; ++u) {
                    a0 = fmaf(wv1[u], sq[r][a2i + 16 + u], a0);
                    a1 = fmaf(wv1[u], sq[r + 4][a2i + 16 + u], a1);
                }
            }
            sqk[r][e]     = a0;
            sqk[r + 4][e] = a1;
        }
        __syncthreads();

        // mini-stage: s = qk·val_w (tid<8) ; biasdot = ctxp·bias_w (tid 8..15) — batched
        if (tid < 8) {
            int g = tid;
            float a = 0.f;
            #pragma unroll 1
            for (int d2 = 0; d2 < D; d2 += 16) {
                float vv[16];
                #pragma unroll
                for (int u = 0; u < 16; ++u) vv[u] = val_w[d2 + u];
                #pragma unroll
                for (int u = 0; u < 16; ++u) a = fmaf(sqk[g][d2 + u], vv[u], a);
            }
            ssv[g] = a;
        } else if (tid < 16) {
            int g = tid - 8;
            float a = 0.f;
            #pragma unroll 1
            for (int e2 = 0; e2 < D; e2 += 16) {
                float vv[16];
                #pragma unroll
                for (int u = 0; u < 16; ++u) vv[u] = bias_w[e2 + u];
                #pragma unroll
                for (int u = 0; u < 16; ++u) a = fmaf(sctxp[g][e2 + u], vv[u], a);
            }
            sbd[g] = a;
        }
        __syncthreads();

        // logits: thread handles l = tid&255 for rows h*4..h*4+3 (h = tid>>8), dbuf loads
        {
            int l = tid & (LQ - 1);
            int h = tid >> 8;                 // 0..1
            int r0 = h * 4;
            float c0 = 0.f, c1v = 0.f, c2 = 0.f, c3 = 0.f;
            float bd0[16], bd1[16];
            #pragma unroll
            for (int u = 0; u < 16; ++u) bd0[u] = baseT[u * LQ + l];
            #pragma unroll 1
            for (int d2 = 0; d2 < D; d2 += 32) {
                #pragma unroll
                for (int u = 0; u < 16; ++u) bd1[u] = baseT[(d2 + 16 + u) * LQ + l];
                #pragma unroll
                for (int u = 0; u < 16; ++u) {
                    float bd = bd0[u];
                    c0  = fmaf(bd, sqk[r0 + 0][d2 + u], c0);
                    c1v = fmaf(bd, sqk[r0 + 1][d2 + u], c1v);
                    c2  = fmaf(bd, sqk[r0 + 2][d2 + u], c2);
                    c3  = fmaf(bd, sqk[r0 + 3][d2 + u], c3);
                }
                if (d2 + 32 < D) {
                    #pragma unroll
                    for (int u = 0; u < 16; ++u) bd0[u] = baseT[(d2 + 32 + u) * LQ + l];
                }
                #pragma unroll
                for (int u = 0; u < 16; ++u) {
                    float bd = bd1[u];
                    c0  = fmaf(bd, sqk[r0 + 0][d2 + 16 + u], c0);
                    c1v = fmaf(bd, sqk[r0 + 1][d2 + 16 + u], c1v);
                    c2  = fmaf(bd, sqk[r0 + 2][d2 + 16 + u], c2);
                    c3  = fmaf(bd, sqk[r0 + 3][d2 + 16 + u], c3);
                }
            }
            float accs[4] = {c0, c1v, c2, c3};
            #pragma unroll
            for (int j = 0; j < 4; ++j) {
                int g = r0 + j;
                int row = srow[g]; int b = row >> 12, t = row & (TQ - 1);
                int ii = t - 1 - l;
                float xl = (ii >= 0) ? x[b * TQ + ii] : 0.f;
                slog[g][l] = __fadd_rn(__fmul_rn(xl, ssv[g]), accs[j]);
            }
        }
        __syncthreads();

        // top-8 + softmax + writes: wave w handles row w (8 waves, all busy)
        {
            int wv = tid >> 6, lane = tid & 63;
            int gg = wv;
            float lv0 = slog[gg][lane], lv1 = slog[gg][lane + 64];
            float lv2 = slog[gg][lane + 128], lv3 = slog[gg][lane + 192];
            const float NEG_INF = -__builtin_inff();
            float w0 = lv0, w1 = lv1, w2 = lv2, w3 = lv3;
            float mx = 0.f, thr = 0.f;
            #pragma unroll
            for (int it = 0; it < 8; ++it) {
                float lm = fmaxf(fmaxf(w0, w1), fmaxf(w2, w3));
                float m = lm;
                #pragma unroll
                for (int off = 32; off >= 1; off >>= 1)
                    m = fmaxf(m, __shfl_xor(m, off, 64));
                if (it == 0) mx = m;
                thr = m;
                if (it < 7) {
                    unsigned long long ball = __ballot(lm == m);
                    int leader = __ffsll(ball) - 1;
                    if (lane == leader) {
                        if (w0 == m)      w0 = NEG_INF;
                        else if (w1 == m) w1 = NEG_INF;
                        else if (w2 == m) w2 = NEG_INF;
                        else              w3 = NEG_INF;
                    }
                }
            }
            int row = srow[gg]; int b = row >> 12, t = row & (TQ - 1);
            float p[4], xlg[4];
            double ps = 0.0;
            float lvs[4] = {lv0, lv1, lv2, lv3};
            #pragma unroll
            for (int j = 0; j < 4; ++j) {
                int l = lane + 64 * j;
                int ii = t - 1 - l;
                xlg[j] = (ii >= 0) ? x[b * TQ + ii] : 0.f;
                p[j] = (lvs[j] >= thr) ? (float)exp((double)__fsub_rn(lvs[j], mx)) : 0.f;
                ps += (double)p[j];
            }
            #pragma unroll
            for (int off = 32; off >= 1; off >>= 1)
                ps += __shfl_xor(ps, off, 64);
            float psf = (float)ps;
            double mud = 0.0;
            #pragma unroll
            for (int j = 0; j < 4; ++j) {
                float wvv = __fdiv_rn(p[j], psf);
                wOut[(size_t)row * LQ + lane + 64 * j] = wvv;
                mud += (double)__fmul_rn(wvv, xlg[j]);
            }
            #pragma unroll
            for (int off = 32; off >= 1; off >>= 1)
                mud += __shfl_xor(mud, off, 64);
            if (lane == 0) {
                float m1 = (float)mud;
                m1 = __fadd_rn(m1, sbd[gg]);
                m1 = __fadd_rn(m1, bias_b[0]);
                muOut[row] = m1;
            }
        }
        __syncthreads();
    }
}

extern "C" void kernel_launch(void* const* d_in, const int* in_sizes, int n_in,
                              void* d_out, int out_size, void* d_ws, size_t ws_size,
                              hipStream_t stream) {
    const float* x         = (const float*)d_in[0];
    const float* lag_embed = (const float*)d_in[1];
    const float* val_w     = (const float*)d_in[2];
    const float* val_b     = (const float*)d_in[3];
    const float* conv_w    = (const float*)d_in[4];
    const float* conv_b    = (const float*)d_in[5];
    const float* ctx_w     = (const float*)d_in[6];
    const float* ctx_b     = (const float*)d_in[7];
    const float* wq        = (const float*)d_in[8];
    const float* wk        = (const float*)d_in[9];
    const float* bias_w    = (const float*)d_in[10];
    const float* bias_b    = (const float*)d_in[11];

    char* wsb = (char*)d_ws;
    double* T2  = (double*)wsb;     // (unused slot kept for layout stability)
    double* g   = T2 + 16384;       // 1152 d
    double* u   = g + 1152;         // 128 d
    double* c1  = u + 128;          // 128 d
    float* gbTf = (float*)(c1 + 128);  // 2304 f
    float* cbvf = gbTf + 2304;         // 256 f
    float* cstf = cbvf + 256;          // 20 f
    int* wcnt  = (int*)(wsb + 163840);
    int* wlist = wcnt + 1;          // WCAP=16384 ints
    float* ctx_wT  = (float*)(wsb + 229504);   // 16384 f
    float* wqT     = ctx_wT + 16384;           // 16384 f
    float* conv_wT = wqT + 16384;              // 1152 f
    float* baseT   = conv_wT + 1152;           // 32768 f

    float* muOut = (float*)d_out;
    float* wOut  = muOut + BQ * TQ;

    hipLaunchKernelGGL(pk12, dim3(D + 2), dim3(256), 0, stream,
                       wk, wq, ctx_w, bias_w, conv_w, conv_b, ctx_b, val_b, lag_embed,
                       u, wcnt, g, c1, ctx_wT, wqT, conv_wT, baseT);
    hipLaunchKernelGGL(pk3, dim3(LQ + 1), dim3(D), 0, stream,
                       lag_embed, val_b, val_w, conv_w, conv_b, ctx_b, bias_w, bias_b,
                       g, c1, u, gbTf, cbvf, cstf);
    hipLaunchKernelGGL(lag_main, dim3(BQ * TQ / 4), dim3(256), 0, stream,
                       x, gbTf, cbvf, cstf, muOut, wOut, wcnt, wlist);
    hipLaunchKernelGGL(fixer, dim3(256), dim3(512), 0, stream,
                       x, wk, val_w, conv_b, ctx_b, bias_w, bias_b,
                       ctx_wT, wqT, conv_wT, baseT, wcnt, wlist, muOut, wOut);
}